// Round 4
// baseline (303.552 us; speedup 1.0000x reference)
//
#include <hip/hip_runtime.h>
#include <math.h>

#define TPB 256

// LDS/ws float layout (shared between prep and main):
//   [0,4704)   wT[j][e]  : dense_w transposed, j-major (float4-friendly along e)
//   4704..4718 csc[15]   4720..4734 css[15]
//   4736..4741 sb[6]     4744..4749 sw[6]     4752 sob
#define OFF_CSC 4704
#define OFF_CSS 4720
#define OFF_SB  4736
#define OFF_SW  4744
#define OFF_SOB 4752
#define TOTF    4756          // padded to multiple of 4
#define TOT4    (TOTF / 4)    // 1189 float4

// ---- prep: 1 block transposes weights + precomputes consts into d_ws ----
__global__ __launch_bounds__(TPB) void prep_kernel(
    const float* __restrict__ dw, const float* __restrict__ db,
    const float* __restrict__ qw, const float* __restrict__ ow,
    const float* __restrict__ ob, float* __restrict__ ws)
{
    const int tid = threadIdx.x;
    for (int i = tid; i < 4704; i += TPB) {   // 784*6
        int e = i / 6;
        int j = i - e * 6;
        ws[j * 784 + e] = dw[i];
    }
    if (tid < 15) { float q = qw[tid]; ws[OFF_CSC + tid] = cosf(q); ws[OFF_CSS + tid] = sinf(q); }
    if (tid < 6)  { ws[OFF_SB + tid] = db[tid]; ws[OFF_SW + tid] = ow[tid]; }
    if (tid == 0) ws[OFF_SOB] = ob[0];
}

// ---- main: wave = 4 groups x 16 lanes; each group handles 4 consecutive
// rows; wave = 16 rows, block = 64 rows. Weights read from LDS (broadcast
// across groups, conflict-free b128). Preamble = coalesced float4 copy. ----
__global__ __launch_bounds__(TPB) void hybrid_kernel(
    const float* __restrict__ inp,   // (B, 784)
    const float* __restrict__ ws,    // prepped consts
    float* __restrict__ out,         // (B, 1)
    int B)
{
    __shared__ float ldsF[TOTF];
    float4* lds4 = (float4*)ldsF;
    const float4* wsrc4 = (const float4*)ws;
    const int tid = threadIdx.x;

    #pragma unroll
    for (int k = 0; k < 5; ++k) {             // ceil(1189/256) = 5
        int i = tid + k * TPB;
        if (i < TOT4) lds4[i] = wsrc4[i];
    }
    __syncthreads();

    const float4* wT4 = lds4;                 // [6][196] float4
    const float* csc = ldsF + OFF_CSC;
    const float* css = ldsF + OFF_CSS;
    const float* sb  = ldsF + OFF_SB;
    const float* sw  = ldsF + OFF_SW;
    const float  sob = ldsF[OFF_SOB];

    const int lane = tid & 63;
    const int grp  = lane >> 4;
    const int gl   = lane & 15;
    const int wave = tid >> 6;
    const int base = blockIdx.x * 64 + wave * 16 + grp * 4;  // rows base..base+3
    if (base >= B) return;

    const float4* x0 = (const float4*)(inp + (size_t)base * 784);  // row = 196 float4

    float acc[4][6];
    #pragma unroll
    for (int r = 0; r < 4; ++r)
        #pragma unroll
        for (int j = 0; j < 6; ++j) acc[r][j] = 0.f;

    // 196 float4/row: 12 full passes of 16 lanes + 4-lane tail
    #pragma unroll 4
    for (int t = 0; t < 12; ++t) {
        const int idx4 = gl + 16 * t;
        float4 xv[4];
        #pragma unroll
        for (int r = 0; r < 4; ++r) xv[r] = x0[r * 196 + idx4];
        #pragma unroll
        for (int j = 0; j < 6; ++j) {
            const float4 wv = wT4[j * 196 + idx4];
            #pragma unroll
            for (int r = 0; r < 4; ++r)
                acc[r][j] += xv[r].x * wv.x + xv[r].y * wv.y
                           + xv[r].z * wv.z + xv[r].w * wv.w;
        }
    }
    if (gl < 4) {
        const int idx4 = 192 + gl;
        float4 xv[4];
        #pragma unroll
        for (int r = 0; r < 4; ++r) xv[r] = x0[r * 196 + idx4];
        #pragma unroll
        for (int j = 0; j < 6; ++j) {
            const float4 wv = wT4[j * 196 + idx4];
            #pragma unroll
            for (int r = 0; r < 4; ++r)
                acc[r][j] += xv[r].x * wv.x + xv[r].y * wv.y
                           + xv[r].z * wv.z + xv[r].w * wv.w;
        }
    }

    // reduce across the 16-lane group (masks 1,2,4,8 stay inside the group)
    #pragma unroll
    for (int m = 1; m <= 8; m <<= 1) {
        #pragma unroll
        for (int r = 0; r < 4; ++r)
            #pragma unroll
            for (int j = 0; j < 6; ++j)
                acc[r][j] += __shfl_xor(acc[r][j], m, 64);
    }

    // ---- epilogue: 4 rows per lane (redundant across the 16 lanes) ----
    const int PI[15] = {0,1,0,2,1,3,0,2,4,1,3,0,2,1,0}; // PYRAMID_PAIRS, j=i+1
    float4 o4;
    float* op = (float*)&o4;
    #pragma unroll
    for (int r = 0; r < 4; ++r) {
        float a[6];
        float hh = 0.f;
        #pragma unroll
        for (int j = 0; j < 6; ++j) {
            a[j] = acc[r][j] + sb[j];
            hh += a[j] * a[j];
        }
        const float inv = rsqrtf(hh);   // hh==0 -> inf -> NaN downstream, matches ref
        #pragma unroll
        for (int j = 0; j < 6; ++j) a[j] *= inv;

        #pragma unroll
        for (int k = 0; k < 15; ++k) {
            const int i = PI[k];
            const float c = csc[k], s = css[k];
            const float ai = a[i], aj = a[i + 1];
            a[i]     = c * ai + s * aj;
            a[i + 1] = c * aj - s * ai;
        }

        float v = sob;
        #pragma unroll
        for (int j = 0; j < 6; ++j) {
            float z = 1.f - 2.f * a[j] * a[j];
            z = isnan(z) ? 0.f : z;     // jnp.where(isnan(z), 0, z)
            v += z * sw[j];
        }
        op[r] = 1.f / (1.f + __expf(-v));
    }

    if (gl == 0) *(float4*)(out + base) = o4;  // 4 consecutive rows, 16B-aligned

}

extern "C" void kernel_launch(void* const* d_in, const int* in_sizes, int n_in,
                              void* d_out, int out_size, void* d_ws, size_t ws_size,
                              hipStream_t stream) {
    const float* inp = (const float*)d_in[0];
    const float* dw  = (const float*)d_in[1];
    const float* db  = (const float*)d_in[2];
    const float* qw  = (const float*)d_in[3];
    const float* ow  = (const float*)d_in[4];
    const float* ob  = (const float*)d_in[5];
    float* out = (float*)d_out;
    float* ws  = (float*)d_ws;

    const int B = in_sizes[0] / 784;          // 65536
    prep_kernel<<<1, TPB, 0, stream>>>(dw, db, qw, ow, ob, ws);
    const int blocks = (B + 63) / 64;         // 64 rows per block
    hybrid_kernel<<<blocks, TPB, 0, stream>>>(inp, ws, out, B);
}

// Round 5
// 292.359 us; speedup vs baseline: 1.0383x; 1.0383x over previous
//
#include <hip/hip_runtime.h>
#include <math.h>

#define TPB 256

// One wave = 4 rows (16 lanes per row). Block of 256 = 16 rows.
// dense_w transposed into LDS as wT[6][784]: conflict-free ds_read_b128 per
// j-column; the wave's 4 groups read identical addresses (LDS broadcast).
// Kernel is HBM-read-bound (205.5 MB of inputs); epilogue redundant per group.
__global__ __launch_bounds__(TPB) void hybrid_kernel(
    const float* __restrict__ inp,   // (B, 784)
    const float* __restrict__ dw,    // (784, 6)
    const float* __restrict__ db,    // (6,)
    const float* __restrict__ qw,    // (15,)
    const float* __restrict__ ow,    // (6, 1)
    const float* __restrict__ ob,    // (1,)
    float* __restrict__ out,         // (B, 1)
    int B)
{
    __shared__ float4 wT4[6 * 196];          // wT[j][e] as float4 along e
    __shared__ float csc[15], css[15];
    __shared__ float sb[8], sw[8];
    __shared__ float sob;

    float* wT = (float*)wT4;
    const int tid = threadIdx.x;

    // ---- once per block: transpose dense_w into LDS, precompute cos/sin ----
    for (int i = tid; i < 4704; i += TPB) {   // 784*6
        int e = i / 6;
        int j = i - e * 6;
        wT[j * 784 + e] = dw[i];
    }
    if (tid < 15) { float q = qw[tid]; csc[tid] = cosf(q); css[tid] = sinf(q); }
    if (tid < 6)  { sb[tid] = db[tid]; sw[tid] = ow[tid]; }
    if (tid == 0) sob = ob[0];
    __syncthreads();

    const int lane = tid & 63;
    const int grp  = lane >> 4;       // 0..3 : which row within the wave
    const int gl   = lane & 15;       // lane within the 16-lane row group
    const int row  = blockIdx.x * 16 + (tid >> 6) * 4 + grp;
    if (row >= B) return;             // no further barriers below

    const float4* x4 = (const float4*)(inp + (size_t)row * 784);

    float acc[6] = {0.f, 0.f, 0.f, 0.f, 0.f, 0.f};

    // 196 float4 per row: 12 full passes of 16 lanes + 4-lane tail
    #pragma unroll 4
    for (int t = 0; t < 12; ++t) {
        const int idx4 = gl + 16 * t;
        const float4 xv = x4[idx4];
        #pragma unroll
        for (int j = 0; j < 6; ++j) {
            const float4 wv = wT4[j * 196 + idx4];
            acc[j] += xv.x * wv.x + xv.y * wv.y + xv.z * wv.z + xv.w * wv.w;
        }
    }
    if (gl < 4) {
        const int idx4 = 192 + gl;
        const float4 xv = x4[idx4];
        #pragma unroll
        for (int j = 0; j < 6; ++j) {
            const float4 wv = wT4[j * 196 + idx4];
            acc[j] += xv.x * wv.x + xv.y * wv.y + xv.z * wv.z + xv.w * wv.w;
        }
    }

    // reduce across the 16-lane group (masks 1,2,4,8 stay inside the group)
    #pragma unroll
    for (int m = 1; m <= 8; m <<= 1) {
        #pragma unroll
        for (int j = 0; j < 6; ++j)
            acc[j] += __shfl_xor(acc[j], m, 64);
    }

    // ---- epilogue (redundant across the 16 lanes; lane gl==0 stores) ----
    float a[6];
    float hh = 0.f;
    #pragma unroll
    for (int j = 0; j < 6; ++j) {
        a[j] = acc[j] + sb[j];
        hh += a[j] * a[j];
    }
    const float inv = rsqrtf(hh);     // hh==0 -> inf -> NaN downstream, matches ref
    #pragma unroll
    for (int j = 0; j < 6; ++j) a[j] *= inv;

    // PYRAMID_PAIRS: second index is always first+1
    const int PI[15] = {0,1,0,2,1,3,0,2,4,1,3,0,2,1,0};
    #pragma unroll
    for (int k = 0; k < 15; ++k) {
        const int i = PI[k];
        const float c = csc[k], s = css[k];
        const float ai = a[i], aj = a[i + 1];
        a[i]     = c * ai + s * aj;
        a[i + 1] = c * aj - s * ai;
    }

    float v = sob;
    #pragma unroll
    for (int j = 0; j < 6; ++j) {
        float z = 1.f - 2.f * a[j] * a[j];
        z = isnan(z) ? 0.f : z;       // jnp.where(isnan(z), 0, z)
        v += z * sw[j];
    }
    const float o = 1.f / (1.f + __expf(-v));

    if (gl == 0) out[row] = o;
}

extern "C" void kernel_launch(void* const* d_in, const int* in_sizes, int n_in,
                              void* d_out, int out_size, void* d_ws, size_t ws_size,
                              hipStream_t stream) {
    const float* inp = (const float*)d_in[0];
    const float* dw  = (const float*)d_in[1];
    const float* db  = (const float*)d_in[2];
    const float* qw  = (const float*)d_in[3];
    const float* ow  = (const float*)d_in[4];
    const float* ob  = (const float*)d_in[5];
    float* out = (float*)d_out;

    const int B = in_sizes[0] / 784;          // 65536
    const int blocks = (B + 15) / 16;         // 16 rows per block
    hybrid_kernel<<<blocks, TPB, 0, stream>>>(inp, dw, db, qw, ow, ob, out, B);
}